// Round 1
// baseline (110.828 us; speedup 1.0000x reference)
//
#include <hip/hip_runtime.h>
#include <hip/hip_bf16.h>

#define NB   16384   // samples
#define ND   2048    // feature dim
#define NG   8       // groups
#define NR   6       // reg outputs
#define NKC  48      // K*C cls outputs
#define NOUT 54      // NR + NKC
#define BM   64      // rows per tile
#define BN   64      // padded output cols
#define BK   64      // k step
#define LDSK 72      // padded LDS stride (shorts)
#define MAXT (NB / BM + NG)   // 264 max tiles

typedef __attribute__((ext_vector_type(8))) short short8_t;
typedef __attribute__((ext_vector_type(4))) float f32x4;

__device__ __forceinline__ unsigned short f2bf(float x) {
    union { float f; unsigned u; } v; v.f = x;
    unsigned r = v.u + 0x7FFFu + ((v.u >> 16) & 1u);   // RNE
    return (unsigned short)(r >> 16);
}

__device__ __forceinline__ short8_t cvt8(float4 a, float4 b) {
    short8_t s;
    s[0] = (short)f2bf(a.x); s[1] = (short)f2bf(a.y);
    s[2] = (short)f2bf(a.z); s[3] = (short)f2bf(a.w);
    s[4] = (short)f2bf(b.x); s[5] = (short)f2bf(b.y);
    s[6] = (short)f2bf(b.z); s[7] = (short)f2bf(b.w);
    return s;
}

// ---- pass 1: histogram of roi ids (wave-aggregated atomics) ----
__global__ void hist_kernel(const int* __restrict__ roi, int* __restrict__ counts) {
    int i = blockIdx.x * 256 + threadIdx.x;   // grid covers exactly NB
    int g = roi[i];
    int lane = threadIdx.x & 63;
    #pragma unroll
    for (int gg = 0; gg < NG; ++gg) {
        unsigned long long m = __ballot(g == gg);
        if (m && lane == (int)(__ffsll((unsigned long long)m) - 1))
            atomicAdd(&counts[gg], (int)__popcll(m));
    }
}

// ---- pass 2: scatter sample indices into group-sorted perm ----
__global__ void scatter_kernel(const int* __restrict__ roi, const int* __restrict__ counts,
                               int* __restrict__ ranks, int* __restrict__ perm) {
    int off[NG];
    int acc = 0;
    #pragma unroll
    for (int gg = 0; gg < NG; ++gg) { off[gg] = acc; acc += counts[gg]; }
    int i = blockIdx.x * 256 + threadIdx.x;
    int g = roi[i];
    int lane = threadIdx.x & 63;
    #pragma unroll
    for (int gg = 0; gg < NG; ++gg) {
        unsigned long long m = __ballot(g == gg);
        if (!m) continue;
        int leader = (int)(__ffsll((unsigned long long)m) - 1);
        int base = 0;
        if (lane == leader) base = atomicAdd(&ranks[gg], (int)__popcll(m));
        base = __shfl(base, leader);
        if (g == gg) {
            int rank = (int)__popcll(m & ((1ull << lane) - 1ull));
            perm[off[gg] + base + rank] = i;
        }
    }
}

// ---- pass 3: grouped skinny GEMM, bf16 MFMA, fused bias + scatter-out ----
__launch_bounds__(256, 2)
__global__ void gemm_kernel(const float* __restrict__ feats,
                            const float* __restrict__ Wreg, const float* __restrict__ breg,
                            const float* __restrict__ Wcls, const float* __restrict__ bcls,
                            const int* __restrict__ counts, const int* __restrict__ perm,
                            float* __restrict__ out) {
    __shared__ __align__(16) short As[BM][LDSK];
    __shared__ __align__(16) short Bs[BN][LDSK];
    __shared__ int sRow[BM];

    // local offsets + cumulative tile starts (uniform, 8 iters)
    int off[NG + 1], ts[NG + 1];
    off[0] = 0; ts[0] = 0;
    #pragma unroll
    for (int gg = 0; gg < NG; ++gg) {
        int c = counts[gg];
        off[gg + 1] = off[gg] + c;
        ts[gg + 1]  = ts[gg] + (c + BM - 1) / BM;
    }
    int b = blockIdx.x;
    if (b >= ts[NG]) return;
    int g = 0;
    #pragma unroll
    for (int gg = 0; gg < NG; ++gg) if (b >= ts[gg + 1]) g = gg + 1;
    int tile  = b - ts[g];
    int goff  = off[g];
    int gcnt  = off[g + 1] - goff;
    int rbase = tile * BM;
    int nvalid = gcnt - rbase; if (nvalid > BM) nvalid = BM;

    int tid = threadIdx.x;
    if (tid < BM) {
        int r = rbase + tid;
        if (r >= gcnt) r = gcnt - 1;   // clamp; stores masked by nvalid
        sRow[tid] = perm[goff + r];
    }
    __syncthreads();

    int rS = tid >> 2;          // 0..63: LDS row staged by this thread
    int cS = (tid & 3) * 16;    // 0/16/32/48: float col base
    const float* wsrc = nullptr;
    if (rS < NR)        wsrc = Wreg + ((size_t)g * NR + rS) * ND;
    else if (rS < NOUT) wsrc = Wcls + ((size_t)g * NKC + (rS - NR)) * ND;

    const float* asrc = feats + (size_t)sRow[rS] * ND + cS;

    int w = tid >> 6, l = tid & 63, lr = l & 15, lq = l >> 4;
    f32x4 acc[4] = {{0,0,0,0},{0,0,0,0},{0,0,0,0},{0,0,0,0}};

    for (int k0 = 0; k0 < ND; k0 += BK) {
        {   // stage A (feats rows, gathered)
            const float* s = asrc + k0;
            float4 v0 = *(const float4*)(s);
            float4 v1 = *(const float4*)(s + 4);
            float4 v2 = *(const float4*)(s + 8);
            float4 v3 = *(const float4*)(s + 12);
            *(short8_t*)&As[rS][cS]     = cvt8(v0, v1);
            *(short8_t*)&As[rS][cS + 8] = cvt8(v2, v3);
        }
        if (wsrc) {   // stage B (weights for this group)
            const float* s = wsrc + k0 + cS;
            float4 v0 = *(const float4*)(s);
            float4 v1 = *(const float4*)(s + 4);
            float4 v2 = *(const float4*)(s + 8);
            float4 v3 = *(const float4*)(s + 12);
            *(short8_t*)&Bs[rS][cS]     = cvt8(v0, v1);
            *(short8_t*)&Bs[rS][cS + 8] = cvt8(v2, v3);
        } else {
            short8_t z = {0,0,0,0,0,0,0,0};
            *(short8_t*)&Bs[rS][cS]     = z;
            *(short8_t*)&Bs[rS][cS + 8] = z;
        }
        __syncthreads();
        #pragma unroll
        for (int kk = 0; kk < 2; ++kk) {
            short8_t af = *(const short8_t*)&As[w * 16 + lr][kk * 32 + lq * 8];
            #pragma unroll
            for (int n = 0; n < 4; ++n) {
                short8_t bf = *(const short8_t*)&Bs[n * 16 + lr][kk * 32 + lq * 8];
                acc[n] = __builtin_amdgcn_mfma_f32_16x16x32_bf16(af, bf, acc[n], 0, 0, 0);
            }
        }
        __syncthreads();
    }

    const int B6 = NB * NR;
    #pragma unroll
    for (int n = 0; n < 4; ++n) {
        #pragma unroll
        for (int j = 0; j < 4; ++j) {
            int row = w * 16 + lq * 4 + j;   // sorted-row within tile
            int col = n * 16 + lr;           // output index
            if (row < nvalid && col < NOUT) {
                int smp = sRow[row];
                float v = acc[n][j];
                if (col < NR) out[smp * NR + col] = v + breg[g * NR + col];
                else          out[B6 + smp * NKC + (col - NR)] = v + bcls[g * NKC + (col - NR)];
            }
        }
    }
}

// ---- fallback (ws too small): exact fp32, one wave per sample ----
__global__ void fallback_kernel(const float* __restrict__ feats, const int* __restrict__ roi,
                                const float* __restrict__ Wreg, const float* __restrict__ breg,
                                const float* __restrict__ Wcls, const float* __restrict__ bcls,
                                float* __restrict__ out) {
    int i = blockIdx.x;
    int lane = threadIdx.x;
    int g = roi[i];
    const float* frow = feats + (size_t)i * ND;
    float f[32];
    #pragma unroll
    for (int q = 0; q < 32; ++q) f[q] = frow[lane + 64 * q];
    for (int o = 0; o < NOUT; ++o) {
        const float* wrow = (o < NR) ? Wreg + ((size_t)g * NR + o) * ND
                                     : Wcls + ((size_t)g * NKC + (o - NR)) * ND;
        float p = 0.f;
        #pragma unroll
        for (int q = 0; q < 32; ++q) p += f[q] * wrow[lane + 64 * q];
        #pragma unroll
        for (int s = 32; s; s >>= 1) p += __shfl_xor(p, s);
        if (lane == 0) {
            if (o < NR) out[i * NR + o] = p + breg[g * NR + o];
            else        out[NB * NR + i * NKC + (o - NR)] = p + bcls[g * NKC + (o - NR)];
        }
    }
}

extern "C" void kernel_launch(void* const* d_in, const int* in_sizes, int n_in,
                              void* d_out, int out_size, void* d_ws, size_t ws_size,
                              hipStream_t stream) {
    const float* feats = (const float*)d_in[0];
    const int*   roi   = (const int*)d_in[1];
    const float* Wreg  = (const float*)d_in[2];
    const float* breg  = (const float*)d_in[3];
    const float* Wcls  = (const float*)d_in[4];
    const float* bcls  = (const float*)d_in[5];
    float* out = (float*)d_out;

    size_t need = (size_t)(64 + NB) * sizeof(int);
    if (ws_size < need) {
        fallback_kernel<<<NB, 64, 0, stream>>>(feats, roi, Wreg, breg, Wcls, bcls, out);
        return;
    }
    int* counts = (int*)d_ws;     // [0..8)
    int* ranks  = counts + 8;     // [8..16)
    int* perm   = counts + 64;    // [64..64+NB)

    hipMemsetAsync(counts, 0, 16 * sizeof(int), stream);
    hist_kernel<<<NB / 256, 256, 0, stream>>>(roi, counts);
    scatter_kernel<<<NB / 256, 256, 0, stream>>>(roi, counts, ranks, perm);
    gemm_kernel<<<MAXT, 256, 0, stream>>>(feats, Wreg, breg, Wcls, bcls, counts, perm, out);
}